// Round 4
// baseline (679.831 us; speedup 1.0000x reference)
//
#include <hip/hip_runtime.h>
#include <hip/hip_fp16.h>
#include <cmath>

constexpr int NPTS = 262144;
constexpr int LVLS = 16;
constexpr int TSZ  = 524288;
constexpr unsigned TMASK = TSZ - 1u;
constexpr unsigned P1 = 2654435761u;
constexpr unsigned P2 = 805459861u;
// packed entry: 3 x uint2 = 24B = [a1.xy|a2.xy][b1.xy|b2.xy][st.xy|pad] as fp16 pairs
constexpr size_t PACKED_BYTES = (size_t)LVLS * TSZ * 24;
// feature planes: 16 levels x 3 dword-planes x NPTS dwords
constexpr size_t FEAT_BYTES = (size_t)LVLS * 3 * NPTS * 4;

struct LevelParams {
  float scale[LVLS];
  int   res[LVLS];
  int   dense[LVLS];
};

typedef __fp16 half2v __attribute__((ext_vector_type(2)));

__device__ __forceinline__ unsigned pkh2(float lo, float hi) {
  half2v r = __builtin_amdgcn_cvt_pkrtz(lo, hi);
  return *reinterpret_cast<unsigned*>(&r);
}
__device__ __forceinline__ float2 uph2(unsigned w) {
  half2v h = *reinterpret_cast<half2v*>(&w);
  return make_float2((float)h.x, (float)h.y);
}

__global__ __launch_bounds__(256)
void repack_tables(const float2* __restrict__ ta1, const float2* __restrict__ ta2,
                   const float2* __restrict__ tb1, const float2* __restrict__ tb2,
                   const float2* __restrict__ tst, uint2* __restrict__ packed)
{
  const size_t i = (size_t)blockIdx.x * 256 + threadIdx.x;   // i = l*TSZ + idx
  const float2 a1 = ta1[i], a2 = ta2[i], b1 = tb1[i], b2 = tb2[i], st = tst[i];
  uint2 e0, e1, e2;
  e0.x = pkh2(a1.x, a1.y); e0.y = pkh2(a2.x, a2.y);
  e1.x = pkh2(b1.x, b1.y); e1.y = pkh2(b2.x, b2.y);
  e2.x = pkh2(st.x, st.y); e2.y = 0u;
  uint2* o = packed + i * 3;
  o[0] = e0; o[1] = e1; o[2] = e2;
}

// ---------------- Kernel A: gather + interpolate + time-blend ----------------
// 2 threads per point: lanes L (role A: tables a1,a2 + st corners 0-3) and
// L+32 (role B: tables b1,b2 + st corners 4-7). Double-buffered level pipeline.
__global__ __launch_bounds__(256)
void ngp_gather(const float* __restrict__ xyzs,
                const uint2* __restrict__ pk,
                unsigned* __restrict__ feat,      // [(l*3+c)*NPTS + p] fp16x2 planes
                float* __restrict__ out,
                LevelParams lp)
{
  const int lane = threadIdx.x & 63;
  const int wid  = threadIdx.x >> 6;
  const int roleB = lane >> 5;                      // 0: lanes 0-31, 1: lanes 32-63
  const int p = (blockIdx.x * 4 + wid) * 32 + (lane & 31);

  // time blend (uniform value, per-thread computed)
  const float t = xyzs[3];
  float ft = t * 16.0f, fr = ft - floorf(ft);
  float prev1 = 1.0f - fr, next1 = 1.0f - prev1;
  const float ss1 = prev1 + next1; prev1 /= ss1; next1 /= ss1;
  ft = t * 20.0f; fr = ft - floorf(ft);
  float prev2 = 1.0f - fr, next2 = 1.0f - prev2;
  const float ss2 = prev2 + next2; prev2 /= ss2; next2 /= ss2;
  const float bw_p = roleB ? prev2 : prev1;
  const float bw_n = roleB ? next2 : next1;

  const float4 xin = reinterpret_cast<const float4*>(xyzs)[p];
  const float px = (xin.x + 1.0f) * 0.5f;
  const float py = (xin.y + 1.0f) * 0.5f;
  const float pz = (xin.z + 1.0f) * 0.5f;

  const int roleOff = roleB;          // entry word: 0 -> a-pair, 1 -> b-pair
  const int stOff   = roleB ? 4 : 0;  // which corners this role sums for static

  const size_t f1base = (size_t)4 * NPTS + (size_t)p * 16 + (roleB ? 8 : 0);
  const size_t f2base = (size_t)20 * NPTS + (size_t)p * 16 + (roleB ? 8 : 0);

  // ---- helpers ----
  auto compute_idx = [&](int l, unsigned (&idx)[8], float (&wv)[8]) {
    const float s = lp.scale[l];
    const int res = lp.res[l];
    const float fx = px * s + 0.5f; const float f0x = floorf(fx); const float wx = fx - f0x;
    const float fy = py * s + 0.5f; const float f0y = floorf(fy); const float wy = fy - f0y;
    const float fz = pz * s + 0.5f; const float f0z = floorf(fz); const float wz = fz - f0z;
    const int ix = (int)f0x, iy = (int)f0y, iz = (int)f0z;
    if (lp.dense[l]) {
      const int r2 = res * res;
      const int bx0 = ix,       bx1 = ix + 1;
      const int by0 = iy * res, by1 = by0 + res;
      const int bz0 = iz * r2,  bz1 = bz0 + r2;
      idx[0] = (unsigned)(bx0 + by0 + bz0);
      idx[1] = (unsigned)(bx1 + by0 + bz0);
      idx[2] = (unsigned)(bx0 + by1 + bz0);
      idx[3] = (unsigned)(bx1 + by1 + bz0);
      idx[4] = (unsigned)(bx0 + by0 + bz1);
      idx[5] = (unsigned)(bx1 + by0 + bz1);
      idx[6] = (unsigned)(bx0 + by1 + bz1);
      idx[7] = (unsigned)(bx1 + by1 + bz1);
    } else {
      const unsigned hx0 = (unsigned)ix,      hx1 = hx0 + 1u;
      const unsigned hy0 = (unsigned)iy * P1, hy1 = hy0 + P1;
      const unsigned hz0 = (unsigned)iz * P2, hz1 = hz0 + P2;
      idx[0] = (hx0 ^ hy0 ^ hz0) & TMASK;
      idx[1] = (hx1 ^ hy0 ^ hz0) & TMASK;
      idx[2] = (hx0 ^ hy1 ^ hz0) & TMASK;
      idx[3] = (hx1 ^ hy1 ^ hz0) & TMASK;
      idx[4] = (hx0 ^ hy0 ^ hz1) & TMASK;
      idx[5] = (hx1 ^ hy0 ^ hz1) & TMASK;
      idx[6] = (hx0 ^ hy1 ^ hz1) & TMASK;
      idx[7] = (hx1 ^ hy1 ^ hz1) & TMASK;
    }
    const float wxa = 1.0f - wx, wya = 1.0f - wy, wza = 1.0f - wz;
    wv[0] = wxa * wya * wza;
    wv[1] = wx  * wya * wza;
    wv[2] = wxa * wy  * wza;
    wv[3] = wx  * wy  * wza;
    wv[4] = wxa * wya * wz;
    wv[5] = wx  * wya * wz;
    wv[6] = wxa * wy  * wz;
    wv[7] = wx  * wy  * wz;
  };

  auto issue = [&](int l, const unsigned (&idx)[8], uint2 (&m)[8], unsigned (&sv)[4]) {
    const uint2* lvl = pk + (size_t)l * (TSZ * 3);
    const unsigned* lvl32 = reinterpret_cast<const unsigned*>(lvl);
    #pragma unroll
    for (int c = 0; c < 8; ++c) m[c] = lvl[idx[c] * 3u + (unsigned)roleOff];
    #pragma unroll
    for (int c = 0; c < 4; ++c) sv[c] = lvl32[(idx[c + stOff] * 3u + 2u) * 2u];
  };

  auto consume = [&](int l, const float (&wv)[8], const uint2 (&m)[8], const unsigned (&sv)[4]) {
    float v10 = 0.f, v11 = 0.f, v20 = 0.f, v21 = 0.f;
    #pragma unroll
    for (int c = 0; c < 8; ++c) {
      const float2 f1 = uph2(m[c].x);
      const float2 f2 = uph2(m[c].y);
      const float w = wv[c];
      v10 += f1.x * w; v11 += f1.y * w;
      v20 += f2.x * w; v21 += f2.y * w;
    }
    float sp0 = 0.f, sp1 = 0.f;
    #pragma unroll
    for (int c = 0; c < 4; ++c) {
      const float2 fs = uph2(sv[c]);
      const float w = wv[c + stOff];
      sp0 += fs.x * w; sp1 += fs.y * w;
    }
    const float st0 = sp0 + __shfl_xor(sp0, 32);
    const float st1 = sp1 + __shfl_xor(sp1, 32);
    const float bl0 = v10 * bw_p + v20 * bw_n;
    const float bl1 = v11 * bw_p + v21 * bw_n;
    feat[(size_t)(l * 3 + roleB) * NPTS + p] = pkh2(bl0, bl1);
    if (!roleB) feat[(size_t)(l * 3 + 2) * NPTS + p] = pkh2(st0, st1);
    if (l >= 12) {
      const size_t fo = (size_t)(l - 12) * 2;
      *reinterpret_cast<float2*>(out + f1base + fo) = make_float2(v10, v11);
      *reinterpret_cast<float2*>(out + f2base + fo) = make_float2(v20, v21);
    }
  };

  // ---- pipelined level loop (double-buffered) ----
  unsigned idxA[8], idxB[8];
  float wvA[8], wvB[8];
  uint2 m0[8], m1[8];
  unsigned s0[4], s1[4];

  compute_idx(0, idxA, wvA);
  issue(0, idxA, m0, s0);
  compute_idx(1, idxB, wvB);

  #pragma unroll
  for (int l = 0; l < LVLS; l += 2) {
    issue(l + 1, idxB, m1, s1);               // prefetch odd level
    consume(l, wvA, m0, s0);                  // consume even level
    if (l + 2 < LVLS) {
      compute_idx(l + 2, idxA, wvA);
      issue(l + 2, idxA, m0, s0);             // prefetch next even level
    }
    consume(l + 1, wvB, m1, s1);              // consume odd level
    if (l + 3 < LVLS) compute_idx(l + 3, idxB, wvB);
  }
}

// ---------------- Kernel B: MLP ----------------
__global__ __launch_bounds__(256)
void ngp_mlp(const float* __restrict__ dirs,
             const unsigned* __restrict__ feat,
             const float* __restrict__ w1,
             const float* __restrict__ w2,
             const float* __restrict__ wc1,
             const float* __restrict__ wc2,
             const float* __restrict__ wc3,
             float* __restrict__ out)
{
  const int n = blockIdx.x * 256 + threadIdx.x;

  float h1[64];
  #pragma unroll
  for (int j = 0; j < 64; ++j) h1[j] = 0.0f;

  for (int l = 0; l < LVLS; ++l) {
    const unsigned d0 = feat[(size_t)(l * 3 + 0) * NPTS + n];
    const unsigned d1 = feat[(size_t)(l * 3 + 1) * NPTS + n];
    const unsigned d2 = feat[(size_t)(l * 3 + 2) * NPTS + n];
    const float2 A = uph2(d0);
    const float2 Bv = uph2(d1);
    const float2 S = uph2(d2);
    const float* wr0 = w1 + (size_t)(2 * l) * 64;
    const float* wr1 = w1 + (size_t)(2 * l + 1) * 64;
    const float* wr2 = w1 + (size_t)(32 + 2 * l) * 64;
    const float* wr3 = w1 + (size_t)(33 + 2 * l) * 64;
    const float* wr4 = w1 + (size_t)(64 + 2 * l) * 64;
    const float* wr5 = w1 + (size_t)(65 + 2 * l) * 64;
    #pragma unroll
    for (int j = 0; j < 64; ++j) {
      float acc = h1[j];
      acc += A.x  * wr0[j];
      acc += A.y  * wr1[j];
      acc += Bv.x * wr2[j];
      acc += Bv.y * wr3[j];
      acc += S.x  * wr4[j];
      acc += S.y  * wr5[j];
      h1[j] = acc;
    }
  }

  // layer 2
  float h2[16];
  #pragma unroll
  for (int j = 0; j < 16; ++j) h2[j] = 0.0f;
  #pragma unroll
  for (int k = 0; k < 64; ++k) {
    const float a = fmaxf(h1[k], 0.0f);
    #pragma unroll
    for (int j = 0; j < 16; ++j) h2[j] += a * w2[k * 16 + j];
  }

  out[(size_t)3 * NPTS + n] = expf(h2[0]);

  // SH degree 4
  const float dx = dirs[(size_t)n * 3 + 0] * 2.0f - 1.0f;
  const float dy = dirs[(size_t)n * 3 + 1] * 2.0f - 1.0f;
  const float dz = dirs[(size_t)n * 3 + 2] * 2.0f - 1.0f;
  const float xy = dx * dy, xz = dx * dz, yz = dy * dz;
  const float x2 = dx * dx, y2 = dy * dy, z2 = dz * dz;
  float sh[16];
  sh[0]  = 0.28209479177387814f;
  sh[1]  = -0.48860251190291987f * dy;
  sh[2]  = 0.48860251190291987f * dz;
  sh[3]  = -0.48860251190291987f * dx;
  sh[4]  = 1.0925484305920792f * xy;
  sh[5]  = -1.0925484305920792f * yz;
  sh[6]  = 0.94617469575756f * z2 - 0.31539156525252005f;
  sh[7]  = -1.0925484305920792f * xz;
  sh[8]  = 0.5462742152960396f * (x2 - y2);
  sh[9]  = 0.5900435899266435f * dy * (-3.0f * x2 + y2);
  sh[10] = 2.890611442640554f * xy * dz;
  sh[11] = 0.4570457994644657f * dy * (1.0f - 5.0f * z2);
  sh[12] = 0.3731763325901154f * dz * (5.0f * z2 - 3.0f);
  sh[13] = 0.4570457994644657f * dx * (1.0f - 5.0f * z2);
  sh[14] = 1.445305721320277f * dz * (x2 - y2);
  sh[15] = 0.5900435899266435f * dx * (-x2 + 3.0f * y2);

  // c1
  float r1[64];
  #pragma unroll
  for (int j = 0; j < 64; ++j) r1[j] = 0.0f;
  #pragma unroll
  for (int k = 0; k < 16; ++k) {
    const float a = sh[k];
    #pragma unroll
    for (int j = 0; j < 64; ++j) r1[j] += a * wc1[(size_t)k * 64 + j];
  }
  #pragma unroll
  for (int k = 0; k < 16; ++k) {
    const float a = h2[k];
    #pragma unroll
    for (int j = 0; j < 64; ++j) r1[j] += a * wc1[(size_t)(16 + k) * 64 + j];
  }
  #pragma unroll
  for (int j = 0; j < 64; ++j) r1[j] = fmaxf(r1[j], 0.0f);

  // c2
  float r2[64];
  #pragma unroll
  for (int j = 0; j < 64; ++j) r2[j] = 0.0f;
  #pragma unroll
  for (int k = 0; k < 64; ++k) {
    const float a = r1[k];
    #pragma unroll
    for (int j = 0; j < 64; ++j) r2[j] += a * wc2[(size_t)k * 64 + j];
  }

  // c3 + sigmoid
  float c0a = 0.f, c1a = 0.f, c2a = 0.f;
  #pragma unroll
  for (int k = 0; k < 64; ++k) {
    const float a = fmaxf(r2[k], 0.0f);
    c0a += a * wc3[k * 3 + 0];
    c1a += a * wc3[k * 3 + 1];
    c2a += a * wc3[k * 3 + 2];
  }
  out[(size_t)n * 3 + 0] = 1.0f / (1.0f + expf(-c0a));
  out[(size_t)n * 3 + 1] = 1.0f / (1.0f + expf(-c1a));
  out[(size_t)n * 3 + 2] = 1.0f / (1.0f + expf(-c2a));
}

// ---------------- Fallback: fused single kernel (round-2 structure) ----------------
template<bool PACKED>
__global__ __launch_bounds__(256)
void ngp_fused(const float* __restrict__ xyzs,
               const float* __restrict__ dirs,
               const float* __restrict__ ta1,
               const float* __restrict__ ta2,
               const float* __restrict__ tb1,
               const float* __restrict__ tb2,
               const float* __restrict__ tst,
               const uint2* __restrict__ pk,
               const float* __restrict__ w1,
               const float* __restrict__ w2,
               const float* __restrict__ wc1,
               const float* __restrict__ wc2,
               const float* __restrict__ wc3,
               float* __restrict__ out,
               LevelParams lp)
{
  const int n = blockIdx.x * 256 + threadIdx.x;
  if (n >= NPTS) return;

  const float t = xyzs[3];
  float ft = t * 16.0f, fr = ft - floorf(ft);
  float prev1 = 1.0f - fr, next1 = 1.0f - prev1;
  const float ss1 = prev1 + next1; prev1 /= ss1; next1 /= ss1;
  ft = t * 20.0f; fr = ft - floorf(ft);
  float prev2 = 1.0f - fr, next2 = 1.0f - prev2;
  const float ss2 = prev2 + next2; prev2 /= ss2; next2 /= ss2;

  const float4 xin = reinterpret_cast<const float4*>(xyzs)[n];
  const float px = (xin.x + 1.0f) * 0.5f;
  const float py = (xin.y + 1.0f) * 0.5f;
  const float pz = (xin.z + 1.0f) * 0.5f;

  float h1[64];
  #pragma unroll
  for (int j = 0; j < 64; ++j) h1[j] = 0.0f;

  const size_t f1base = (size_t)4 * NPTS + (size_t)n * 16;
  const size_t f2base = (size_t)20 * NPTS + (size_t)n * 16;

  for (int l = 0; l < LVLS; ++l) {
    const float s = lp.scale[l];
    const int res = lp.res[l];
    const float fx = px * s + 0.5f; const float f0x = floorf(fx); const float wx = fx - f0x;
    const float fy = py * s + 0.5f; const float f0y = floorf(fy); const float wy = fy - f0y;
    const float fz = pz * s + 0.5f; const float f0z = floorf(fz); const float wz = fz - f0z;
    const int ix = (int)f0x, iy = (int)f0y, iz = (int)f0z;

    unsigned idx[8];
    if (lp.dense[l]) {
      const int r2 = res * res;
      const int bx0 = ix,       bx1 = ix + 1;
      const int by0 = iy * res, by1 = by0 + res;
      const int bz0 = iz * r2,  bz1 = bz0 + r2;
      idx[0] = (unsigned)(bx0 + by0 + bz0);
      idx[1] = (unsigned)(bx1 + by0 + bz0);
      idx[2] = (unsigned)(bx0 + by1 + bz0);
      idx[3] = (unsigned)(bx1 + by1 + bz0);
      idx[4] = (unsigned)(bx0 + by0 + bz1);
      idx[5] = (unsigned)(bx1 + by0 + bz1);
      idx[6] = (unsigned)(bx0 + by1 + bz1);
      idx[7] = (unsigned)(bx1 + by1 + bz1);
    } else {
      const unsigned hx0 = (unsigned)ix,      hx1 = hx0 + 1u;
      const unsigned hy0 = (unsigned)iy * P1, hy1 = hy0 + P1;
      const unsigned hz0 = (unsigned)iz * P2, hz1 = hz0 + P2;
      idx[0] = (hx0 ^ hy0 ^ hz0) & TMASK;
      idx[1] = (hx1 ^ hy0 ^ hz0) & TMASK;
      idx[2] = (hx0 ^ hy1 ^ hz0) & TMASK;
      idx[3] = (hx1 ^ hy1 ^ hz0) & TMASK;
      idx[4] = (hx0 ^ hy0 ^ hz1) & TMASK;
      idx[5] = (hx1 ^ hy0 ^ hz1) & TMASK;
      idx[6] = (hx0 ^ hy1 ^ hz1) & TMASK;
      idx[7] = (hx1 ^ hy1 ^ hz1) & TMASK;
    }

    const float wxa = 1.0f - wx, wya = 1.0f - wy, wza = 1.0f - wz;
    float wv[8];
    wv[0] = wxa * wya * wza;
    wv[1] = wx  * wya * wza;
    wv[2] = wxa * wy  * wza;
    wv[3] = wx  * wy  * wza;
    wv[4] = wxa * wya * wz;
    wv[5] = wx  * wya * wz;
    wv[6] = wxa * wy  * wz;
    wv[7] = wx  * wy  * wz;

    float a10 = 0.f, a11 = 0.f, a20 = 0.f, a21 = 0.f;
    float b10 = 0.f, b11 = 0.f, b20 = 0.f, b21 = 0.f;
    float st0 = 0.f, st1 = 0.f;
    const size_t lbase = (size_t)l * TSZ;

    if constexpr (PACKED) {
      uint2 e0[8], e1[8], e2[8];
      #pragma unroll
      for (int c = 0; c < 8; ++c) {
        const uint2* pp = pk + (lbase + idx[c]) * 3;
        e0[c] = pp[0]; e1[c] = pp[1]; e2[c] = pp[2];
      }
      #pragma unroll
      for (int c = 0; c < 8; ++c) {
        const float w = wv[c];
        float2 f;
        f = uph2(e0[c].x); a10 += f.x * w; a11 += f.y * w;
        f = uph2(e0[c].y); a20 += f.x * w; a21 += f.y * w;
        f = uph2(e1[c].x); b10 += f.x * w; b11 += f.y * w;
        f = uph2(e1[c].y); b20 += f.x * w; b21 += f.y * w;
        f = uph2(e2[c].x); st0 += f.x * w; st1 += f.y * w;
      }
    } else {
      const float2* ba1 = reinterpret_cast<const float2*>(ta1) + lbase;
      const float2* ba2 = reinterpret_cast<const float2*>(ta2) + lbase;
      const float2* bb1 = reinterpret_cast<const float2*>(tb1) + lbase;
      const float2* bb2 = reinterpret_cast<const float2*>(tb2) + lbase;
      const float2* bst = reinterpret_cast<const float2*>(tst) + lbase;
      float2 va1[8], va2[8], vb1[8], vb2[8], vst[8];
      #pragma unroll
      for (int c = 0; c < 8; ++c) {
        const unsigned id = idx[c];
        va1[c] = ba1[id]; va2[c] = ba2[id]; vb1[c] = bb1[id];
        vb2[c] = bb2[id]; vst[c] = bst[id];
      }
      #pragma unroll
      for (int c = 0; c < 8; ++c) {
        const float w = wv[c];
        a10 += va1[c].x * w; a11 += va1[c].y * w;
        a20 += va2[c].x * w; a21 += va2[c].y * w;
        b10 += vb1[c].x * w; b11 += vb1[c].y * w;
        b20 += vb2[c].x * w; b21 += vb2[c].y * w;
        st0 += vst[c].x * w; st1 += vst[c].y * w;
      }
    }

    const float ba0f = a10 * prev1 + a20 * next1;
    const float ba1f = a11 * prev1 + a21 * next1;
    const float bb0f = b10 * prev2 + b20 * next2;
    const float bb1f = b11 * prev2 + b21 * next2;

    const float* wr0 = w1 + (size_t)(2 * l) * 64;
    const float* wr1 = w1 + (size_t)(2 * l + 1) * 64;
    const float* wr2 = w1 + (size_t)(32 + 2 * l) * 64;
    const float* wr3 = w1 + (size_t)(33 + 2 * l) * 64;
    const float* wr4 = w1 + (size_t)(64 + 2 * l) * 64;
    const float* wr5 = w1 + (size_t)(65 + 2 * l) * 64;
    #pragma unroll
    for (int j = 0; j < 64; ++j) {
      float acc = h1[j];
      acc += ba0f * wr0[j];
      acc += ba1f * wr1[j];
      acc += bb0f * wr2[j];
      acc += bb1f * wr3[j];
      acc += st0  * wr4[j];
      acc += st1  * wr5[j];
      h1[j] = acc;
    }

    if (l >= 12) {
      const size_t fo = (size_t)(l - 12) * 2;
      float2* o;
      o = reinterpret_cast<float2*>(out + f1base + fo);     *o = make_float2(a10, a11);
      o = reinterpret_cast<float2*>(out + f1base + 8 + fo); *o = make_float2(b10, b11);
      o = reinterpret_cast<float2*>(out + f2base + fo);     *o = make_float2(a20, a21);
      o = reinterpret_cast<float2*>(out + f2base + 8 + fo); *o = make_float2(b20, b21);
    }
  }

  float h2[16];
  #pragma unroll
  for (int j = 0; j < 16; ++j) h2[j] = 0.0f;
  #pragma unroll
  for (int k = 0; k < 64; ++k) {
    const float a = fmaxf(h1[k], 0.0f);
    #pragma unroll
    for (int j = 0; j < 16; ++j) h2[j] += a * w2[k * 16 + j];
  }

  out[(size_t)3 * NPTS + n] = expf(h2[0]);

  const float dx = dirs[(size_t)n * 3 + 0] * 2.0f - 1.0f;
  const float dy = dirs[(size_t)n * 3 + 1] * 2.0f - 1.0f;
  const float dz = dirs[(size_t)n * 3 + 2] * 2.0f - 1.0f;
  const float xy = dx * dy, xz = dx * dz, yz = dy * dz;
  const float x2 = dx * dx, y2 = dy * dy, z2 = dz * dz;
  float sh[16];
  sh[0]  = 0.28209479177387814f;
  sh[1]  = -0.48860251190291987f * dy;
  sh[2]  = 0.48860251190291987f * dz;
  sh[3]  = -0.48860251190291987f * dx;
  sh[4]  = 1.0925484305920792f * xy;
  sh[5]  = -1.0925484305920792f * yz;
  sh[6]  = 0.94617469575756f * z2 - 0.31539156525252005f;
  sh[7]  = -1.0925484305920792f * xz;
  sh[8]  = 0.5462742152960396f * (x2 - y2);
  sh[9]  = 0.5900435899266435f * dy * (-3.0f * x2 + y2);
  sh[10] = 2.890611442640554f * xy * dz;
  sh[11] = 0.4570457994644657f * dy * (1.0f - 5.0f * z2);
  sh[12] = 0.3731763325901154f * dz * (5.0f * z2 - 3.0f);
  sh[13] = 0.4570457994644657f * dx * (1.0f - 5.0f * z2);
  sh[14] = 1.445305721320277f * dz * (x2 - y2);
  sh[15] = 0.5900435899266435f * dx * (-x2 + 3.0f * y2);

  float r1[64];
  #pragma unroll
  for (int j = 0; j < 64; ++j) r1[j] = 0.0f;
  #pragma unroll
  for (int k = 0; k < 16; ++k) {
    const float a = sh[k];
    #pragma unroll
    for (int j = 0; j < 64; ++j) r1[j] += a * wc1[(size_t)k * 64 + j];
  }
  #pragma unroll
  for (int k = 0; k < 16; ++k) {
    const float a = h2[k];
    #pragma unroll
    for (int j = 0; j < 64; ++j) r1[j] += a * wc1[(size_t)(16 + k) * 64 + j];
  }
  #pragma unroll
  for (int j = 0; j < 64; ++j) r1[j] = fmaxf(r1[j], 0.0f);

  float r2[64];
  #pragma unroll
  for (int j = 0; j < 64; ++j) r2[j] = 0.0f;
  #pragma unroll
  for (int k = 0; k < 64; ++k) {
    const float a = r1[k];
    #pragma unroll
    for (int j = 0; j < 64; ++j) r2[j] += a * wc2[(size_t)k * 64 + j];
  }

  float c0a = 0.f, c1a = 0.f, c2a = 0.f;
  #pragma unroll
  for (int k = 0; k < 64; ++k) {
    const float a = fmaxf(r2[k], 0.0f);
    c0a += a * wc3[k * 3 + 0];
    c1a += a * wc3[k * 3 + 1];
    c2a += a * wc3[k * 3 + 2];
  }
  out[(size_t)n * 3 + 0] = 1.0f / (1.0f + expf(-c0a));
  out[(size_t)n * 3 + 1] = 1.0f / (1.0f + expf(-c1a));
  out[(size_t)n * 3 + 2] = 1.0f / (1.0f + expf(-c2a));
}

extern "C" void kernel_launch(void* const* d_in, const int* in_sizes, int n_in,
                              void* d_out, int out_size, void* d_ws, size_t ws_size,
                              hipStream_t stream) {
  const float* xyzs = (const float*)d_in[0];
  const float* dirs = (const float*)d_in[1];
  const float* ta1  = (const float*)d_in[2];
  const float* ta2  = (const float*)d_in[3];
  const float* tb1  = (const float*)d_in[4];
  const float* tb2  = (const float*)d_in[5];
  const float* tst  = (const float*)d_in[6];
  const float* w1   = (const float*)d_in[7];
  const float* w2   = (const float*)d_in[8];
  const float* wc1  = (const float*)d_in[9];
  const float* wc2  = (const float*)d_in[10];
  const float* wc3  = (const float*)d_in[11];

  LevelParams lp;
  const double B = exp(log(4096.0 / 16.0) / 15.0);
  for (int l = 0; l < LVLS; ++l) {
    const double s = 16.0 * pow(B, (double)l) - 1.0;
    lp.scale[l] = (float)s;
    const int res = (int)ceil(s) + 1;
    lp.res[l] = res;
    lp.dense[l] = ((long long)res * res * res <= (long long)TSZ) ? 1 : 0;
  }

  if (ws_size >= PACKED_BYTES + FEAT_BYTES) {
    uint2* packed = (uint2*)d_ws;
    unsigned* feat = (unsigned*)((char*)d_ws + PACKED_BYTES);
    repack_tables<<<(LVLS * TSZ) / 256, 256, 0, stream>>>(
        (const float2*)ta1, (const float2*)ta2, (const float2*)tb1,
        (const float2*)tb2, (const float2*)tst, packed);
    ngp_gather<<<NPTS / 128, 256, 0, stream>>>(xyzs, packed, feat, (float*)d_out, lp);
    ngp_mlp<<<NPTS / 256, 256, 0, stream>>>(dirs, feat, w1, w2, wc1, wc2, wc3,
                                            (float*)d_out);
  } else if (ws_size >= PACKED_BYTES) {
    uint2* packed = (uint2*)d_ws;
    repack_tables<<<(LVLS * TSZ) / 256, 256, 0, stream>>>(
        (const float2*)ta1, (const float2*)ta2, (const float2*)tb1,
        (const float2*)tb2, (const float2*)tst, packed);
    ngp_fused<true><<<NPTS / 256, 256, 0, stream>>>(
        xyzs, dirs, ta1, ta2, tb1, tb2, tst, packed,
        w1, w2, wc1, wc2, wc3, (float*)d_out, lp);
  } else {
    ngp_fused<false><<<NPTS / 256, 256, 0, stream>>>(
        xyzs, dirs, ta1, ta2, tb1, tb2, tst, nullptr,
        w1, w2, wc1, wc2, wc3, (float*)d_out, lp);
  }
}

// Round 5
// 588.480 us; speedup vs baseline: 1.1552x; 1.1552x over previous
//
#include <hip/hip_runtime.h>
#include <cmath>

constexpr int NPTS = 262144;
constexpr int LVLS = 16;
constexpr int TSZ  = 524288;
constexpr unsigned TMASK = TSZ - 1u;
constexpr unsigned P1 = 2654435761u;
constexpr unsigned P2 = 805459861u;

// workspace layout (bytes)
constexpr size_t PA_BYTES   = (size_t)LVLS * TSZ * 8;   // a1,a2 fp16x4 = 8B entries
constexpr size_t PB_BYTES   = (size_t)LVLS * TSZ * 8;   // b1,b2
constexpr size_t PST_BYTES  = (size_t)LVLS * TSZ * 4;   // st fp16x2
constexpr size_t FEAT_BYTES = (size_t)LVLS * 3 * NPTS * 4;
constexpr int    WP_W1 = 0,    WP_W1N = 48 * 64;         // w1 pairs  [48][64]
constexpr int    WP_W2 = 3072, WP_W2N = 32 * 16;         // w2 pairs  [32][16]
constexpr int    WP_C1 = 3584, WP_C1N = 16 * 64;         // wc1 pairs [16][64]
constexpr int    WP_C2 = 4608, WP_C2N = 32 * 64;         // wc2 pairs [32][64]
constexpr size_t WP_BYTES = 6656 * 4;
constexpr size_t WS_NEED = PA_BYTES + PB_BYTES + PST_BYTES + FEAT_BYTES + WP_BYTES;

typedef __fp16 half2v __attribute__((ext_vector_type(2)));

__device__ __forceinline__ half2v pkh(float lo, float hi) {
  return __builtin_amdgcn_cvt_pkrtz(lo, hi);
}
__device__ __forceinline__ unsigned pkh2(float lo, float hi) {
  half2v r = __builtin_amdgcn_cvt_pkrtz(lo, hi);
  return *reinterpret_cast<unsigned*>(&r);
}
__device__ __forceinline__ half2v ash2(unsigned w) {
  return *reinterpret_cast<half2v*>(&w);
}
__device__ __forceinline__ float2 uph2(unsigned w) {
  half2v h = ash2(w);
  return make_float2((float)h.x, (float)h.y);
}

#if __has_builtin(__builtin_amdgcn_fdot2)
__device__ __forceinline__ float DOT2(half2v a, half2v b, float c) {
  return __builtin_amdgcn_fdot2(a, b, c, false);
}
#else
__device__ __forceinline__ float DOT2(half2v a, half2v b, float c) {
  return c + (float)a.x * (float)b.x + (float)a.y * (float)b.y;
}
#endif

// scheduling: units = (level, kind) where kind 0=A(a1,a2) 1=B(b1,b2) 2=ST
constexpr int MAXU = 20;
struct Sched {
  float scale[LVLS];
  int   res[LVLS];
  int   dense[LVLS];
  int   nblocks[8];                 // per-XCD block count (= cnt*1024)
  unsigned char ukind[8][MAXU];
  unsigned char ulevel[8][MAXU];
};

// ---------------- repack: 5 fp32 tables -> 3 fp16 sub-tables ----------------
__global__ __launch_bounds__(256)
void repack3(const float2* __restrict__ ta1, const float2* __restrict__ ta2,
             const float2* __restrict__ tb1, const float2* __restrict__ tb2,
             const float2* __restrict__ tst,
             uint2* __restrict__ PA, uint2* __restrict__ PB, unsigned* __restrict__ PST)
{
  const size_t i = (size_t)blockIdx.x * 256 + threadIdx.x;   // i = l*TSZ + idx
  const float2 a1 = ta1[i], a2 = ta2[i], b1 = tb1[i], b2 = tb2[i], st = tst[i];
  uint2 ea, eb;
  ea.x = pkh2(a1.x, a1.y); ea.y = pkh2(a2.x, a2.y);
  eb.x = pkh2(b1.x, b1.y); eb.y = pkh2(b2.x, b2.y);
  PA[i] = ea;
  PB[i] = eb;
  PST[i] = pkh2(st.x, st.y);
}

// ---------------- weight conversion to fp16 pairs ----------------
__global__ void wconv(const float* __restrict__ w1, const float* __restrict__ w2,
                      const float* __restrict__ wc1, const float* __restrict__ wc2,
                      unsigned* __restrict__ wp)
{
  const int tid = threadIdx.x;
  for (int i = tid; i < WP_W1N; i += 256) {
    const int r = i >> 6, j = i & 63;
    wp[WP_W1 + i] = pkh2(w1[(2 * r) * 64 + j], w1[(2 * r + 1) * 64 + j]);
  }
  for (int i = tid; i < WP_W2N; i += 256) {
    const int r = i >> 4, j = i & 15;
    wp[WP_W2 + i] = pkh2(w2[(2 * r) * 16 + j], w2[(2 * r + 1) * 16 + j]);
  }
  for (int i = tid; i < WP_C1N; i += 256) {
    const int r = i >> 6, j = i & 63;
    wp[WP_C1 + i] = pkh2(wc1[(2 * r) * 64 + j], wc1[(2 * r + 1) * 64 + j]);
  }
  for (int i = tid; i < WP_C2N; i += 256) {
    const int r = i >> 6, j = i & 63;
    wp[WP_C2 + i] = pkh2(wc2[(2 * r) * 64 + j], wc2[(2 * r + 1) * 64 + j]);
  }
}

// ---------------- gather: unit-phased, XCD-affine ----------------
__global__ __launch_bounds__(256)
void ngp_gather(const float* __restrict__ xyzs,
                const uint2* __restrict__ PA, const uint2* __restrict__ PB,
                const unsigned* __restrict__ PST,
                unsigned* __restrict__ feat, float* __restrict__ out, Sched sc)
{
  const int k = blockIdx.x & 7;          // XCD affinity (round-robin heuristic)
  const int j = blockIdx.x >> 3;
  if (j >= sc.nblocks[k]) return;
  const int u = j >> 10;                 // unit slot on this XCD
  const int chunk = j & 1023;
  const int kind = sc.ukind[k][u];
  const int l = sc.ulevel[k][u];
  const int p = (chunk << 8) + threadIdx.x;

  const float4 xin = reinterpret_cast<const float4*>(xyzs)[p];
  const float px = (xin.x + 1.0f) * 0.5f;
  const float py = (xin.y + 1.0f) * 0.5f;
  const float pz = (xin.z + 1.0f) * 0.5f;

  // indices + trilinear weights for level l
  const float s = sc.scale[l];
  const int res = sc.res[l];
  const float fx = px * s + 0.5f; const float f0x = floorf(fx); const float wx = fx - f0x;
  const float fy = py * s + 0.5f; const float f0y = floorf(fy); const float wy = fy - f0y;
  const float fz = pz * s + 0.5f; const float f0z = floorf(fz); const float wz = fz - f0z;
  const int ix = (int)f0x, iy = (int)f0y, iz = (int)f0z;

  unsigned idx[8];
  if (sc.dense[l]) {
    const int r2 = res * res;
    const int bx0 = ix,       bx1 = ix + 1;
    const int by0 = iy * res, by1 = by0 + res;
    const int bz0 = iz * r2,  bz1 = bz0 + r2;
    idx[0] = (unsigned)(bx0 + by0 + bz0);
    idx[1] = (unsigned)(bx1 + by0 + bz0);
    idx[2] = (unsigned)(bx0 + by1 + bz0);
    idx[3] = (unsigned)(bx1 + by1 + bz0);
    idx[4] = (unsigned)(bx0 + by0 + bz1);
    idx[5] = (unsigned)(bx1 + by0 + bz1);
    idx[6] = (unsigned)(bx0 + by1 + bz1);
    idx[7] = (unsigned)(bx1 + by1 + bz1);
  } else {
    const unsigned hx0 = (unsigned)ix,      hx1 = hx0 + 1u;
    const unsigned hy0 = (unsigned)iy * P1, hy1 = hy0 + P1;
    const unsigned hz0 = (unsigned)iz * P2, hz1 = hz0 + P2;
    idx[0] = (hx0 ^ hy0 ^ hz0) & TMASK;
    idx[1] = (hx1 ^ hy0 ^ hz0) & TMASK;
    idx[2] = (hx0 ^ hy1 ^ hz0) & TMASK;
    idx[3] = (hx1 ^ hy1 ^ hz0) & TMASK;
    idx[4] = (hx0 ^ hy0 ^ hz1) & TMASK;
    idx[5] = (hx1 ^ hy0 ^ hz1) & TMASK;
    idx[6] = (hx0 ^ hy1 ^ hz1) & TMASK;
    idx[7] = (hx1 ^ hy1 ^ hz1) & TMASK;
  }

  const float wxa = 1.0f - wx, wya = 1.0f - wy, wza = 1.0f - wz;
  float wv[8];
  wv[0] = wxa * wya * wza;
  wv[1] = wx  * wya * wza;
  wv[2] = wxa * wy  * wza;
  wv[3] = wx  * wy  * wza;
  wv[4] = wxa * wya * wz;
  wv[5] = wx  * wya * wz;
  wv[6] = wxa * wy  * wz;
  wv[7] = wx  * wy  * wz;

  if (kind == 2) {
    // static table: 8 x 4B gathers
    const unsigned* tb = PST + (size_t)l * TSZ;
    unsigned v[8];
    #pragma unroll
    for (int c = 0; c < 8; ++c) v[c] = tb[idx[c]];
    float st0 = 0.f, st1 = 0.f;
    #pragma unroll
    for (int c = 0; c < 8; ++c) {
      const float2 f = uph2(v[c]);
      st0 += f.x * wv[c]; st1 += f.y * wv[c];
    }
    feat[(size_t)(l * 3 + 2) * NPTS + p] = pkh2(st0, st1);
  } else {
    // time blend weights (t uniform)
    const float t = xyzs[3];
    const float mul = (kind == 0) ? 16.0f : 20.0f;
    float ft = t * mul, fr = ft - floorf(ft);
    float bp = 1.0f - fr, bn = 1.0f - bp;
    const float ss = bp + bn; bp /= ss; bn /= ss;

    const uint2* tb = ((kind == 0) ? PA : PB) + (size_t)l * TSZ;
    uint2 m[8];
    #pragma unroll
    for (int c = 0; c < 8; ++c) m[c] = tb[idx[c]];
    float v10 = 0.f, v11 = 0.f, v20 = 0.f, v21 = 0.f;
    #pragma unroll
    for (int c = 0; c < 8; ++c) {
      const float2 f1 = uph2(m[c].x);
      const float2 f2 = uph2(m[c].y);
      const float w = wv[c];
      v10 += f1.x * w; v11 += f1.y * w;
      v20 += f2.x * w; v21 += f2.y * w;
    }
    const float bl0 = v10 * bp + v20 * bn;
    const float bl1 = v11 * bp + v21 * bn;
    feat[(size_t)(l * 3 + kind) * NPTS + p] = pkh2(bl0, bl1);

    if (l >= 12) {
      const size_t off8 = (kind == 1) ? 8 : 0;
      const size_t fo = (size_t)(l - 12) * 2 + off8;
      const size_t f1base = (size_t)4 * NPTS + (size_t)p * 16;
      const size_t f2base = (size_t)20 * NPTS + (size_t)p * 16;
      *reinterpret_cast<float2*>(out + f1base + fo) = make_float2(v10, v11);
      *reinterpret_cast<float2*>(out + f2base + fo) = make_float2(v20, v21);
    }
  }
}

// ---------------- MLP with v_dot2_f32_f16 ----------------
__global__ __launch_bounds__(256)
void ngp_mlp(const float* __restrict__ dirs,
             const unsigned* __restrict__ feat,
             const unsigned* __restrict__ wp,
             const float* __restrict__ wc3,
             float* __restrict__ out)
{
  const int n = blockIdx.x * 256 + threadIdx.x;
  const half2v* w1p = reinterpret_cast<const half2v*>(wp + WP_W1);
  const half2v* w2p = reinterpret_cast<const half2v*>(wp + WP_W2);
  const half2v* c1p = reinterpret_cast<const half2v*>(wp + WP_C1);
  const half2v* c2p = reinterpret_cast<const half2v*>(wp + WP_C2);

  float h1[64];
  #pragma unroll
  for (int j = 0; j < 64; ++j) h1[j] = 0.0f;

  for (int l = 0; l < LVLS; ++l) {
    const half2v A2 = ash2(feat[(size_t)(l * 3 + 0) * NPTS + n]);
    const half2v B2 = ash2(feat[(size_t)(l * 3 + 1) * NPTS + n]);
    const half2v S2 = ash2(feat[(size_t)(l * 3 + 2) * NPTS + n]);
    #pragma unroll
    for (int j = 0; j < 64; ++j) {
      float acc = h1[j];
      acc = DOT2(A2, w1p[l * 64 + j], acc);
      acc = DOT2(B2, w1p[(16 + l) * 64 + j], acc);
      acc = DOT2(S2, w1p[(32 + l) * 64 + j], acc);
      h1[j] = acc;
    }
  }

  // layer 2: h2 = relu(h1) @ w2
  float h2[16];
  #pragma unroll
  for (int j = 0; j < 16; ++j) h2[j] = 0.0f;
  #pragma unroll
  for (int k = 0; k < 32; ++k) {
    const half2v hp = pkh(fmaxf(h1[2 * k], 0.0f), fmaxf(h1[2 * k + 1], 0.0f));
    #pragma unroll
    for (int j = 0; j < 16; ++j) h2[j] = DOT2(hp, w2p[k * 16 + j], h2[j]);
  }

  out[(size_t)3 * NPTS + n] = expf(h2[0]);

  // SH degree 4
  const float dx = dirs[(size_t)n * 3 + 0] * 2.0f - 1.0f;
  const float dy = dirs[(size_t)n * 3 + 1] * 2.0f - 1.0f;
  const float dz = dirs[(size_t)n * 3 + 2] * 2.0f - 1.0f;
  const float xy = dx * dy, xz = dx * dz, yz = dy * dz;
  const float x2 = dx * dx, y2 = dy * dy, z2 = dz * dz;
  float sh[16];
  sh[0]  = 0.28209479177387814f;
  sh[1]  = -0.48860251190291987f * dy;
  sh[2]  = 0.48860251190291987f * dz;
  sh[3]  = -0.48860251190291987f * dx;
  sh[4]  = 1.0925484305920792f * xy;
  sh[5]  = -1.0925484305920792f * yz;
  sh[6]  = 0.94617469575756f * z2 - 0.31539156525252005f;
  sh[7]  = -1.0925484305920792f * xz;
  sh[8]  = 0.5462742152960396f * (x2 - y2);
  sh[9]  = 0.5900435899266435f * dy * (-3.0f * x2 + y2);
  sh[10] = 2.890611442640554f * xy * dz;
  sh[11] = 0.4570457994644657f * dy * (1.0f - 5.0f * z2);
  sh[12] = 0.3731763325901154f * dz * (5.0f * z2 - 3.0f);
  sh[13] = 0.4570457994644657f * dx * (1.0f - 5.0f * z2);
  sh[14] = 1.445305721320277f * dz * (x2 - y2);
  sh[15] = 0.5900435899266435f * dx * (-x2 + 3.0f * y2);

  // c1: r1 = relu(ch @ wc1), ch = [sh | h2] as 16 fp16 pairs
  half2v chp[16];
  #pragma unroll
  for (int r = 0; r < 8; ++r) chp[r] = pkh(sh[2 * r], sh[2 * r + 1]);
  #pragma unroll
  for (int r = 0; r < 8; ++r) chp[8 + r] = pkh(h2[2 * r], h2[2 * r + 1]);
  float r1[64];
  #pragma unroll
  for (int j = 0; j < 64; ++j) r1[j] = 0.0f;
  #pragma unroll
  for (int k = 0; k < 16; ++k) {
    const half2v cp = chp[k];
    #pragma unroll
    for (int j = 0; j < 64; ++j) r1[j] = DOT2(cp, c1p[k * 64 + j], r1[j]);
  }

  // c2: r2 = r1relu @ wc2
  float r2[64];
  #pragma unroll
  for (int j = 0; j < 64; ++j) r2[j] = 0.0f;
  #pragma unroll
  for (int k = 0; k < 32; ++k) {
    const half2v rp = pkh(fmaxf(r1[2 * k], 0.0f), fmaxf(r1[2 * k + 1], 0.0f));
    #pragma unroll
    for (int j = 0; j < 64; ++j) r2[j] = DOT2(rp, c2p[k * 64 + j], r2[j]);
  }

  // c3 + sigmoid (fp32)
  float c0a = 0.f, c1a = 0.f, c2a = 0.f;
  #pragma unroll
  for (int k = 0; k < 64; ++k) {
    const float a = fmaxf(r2[k], 0.0f);
    c0a += a * wc3[k * 3 + 0];
    c1a += a * wc3[k * 3 + 1];
    c2a += a * wc3[k * 3 + 2];
  }
  out[(size_t)n * 3 + 0] = 1.0f / (1.0f + expf(-c0a));
  out[(size_t)n * 3 + 1] = 1.0f / (1.0f + expf(-c1a));
  out[(size_t)n * 3 + 2] = 1.0f / (1.0f + expf(-c2a));
}

// ---------------- fallback: fused fp32 (no workspace) ----------------
__global__ __launch_bounds__(256)
void ngp_fused(const float* __restrict__ xyzs, const float* __restrict__ dirs,
               const float* __restrict__ ta1, const float* __restrict__ ta2,
               const float* __restrict__ tb1, const float* __restrict__ tb2,
               const float* __restrict__ tst,
               const float* __restrict__ w1, const float* __restrict__ w2,
               const float* __restrict__ wc1, const float* __restrict__ wc2,
               const float* __restrict__ wc3, float* __restrict__ out, Sched sc)
{
  const int n = blockIdx.x * 256 + threadIdx.x;
  if (n >= NPTS) return;

  const float t = xyzs[3];
  float ft = t * 16.0f, fr = ft - floorf(ft);
  float prev1 = 1.0f - fr, next1 = 1.0f - prev1;
  const float ss1 = prev1 + next1; prev1 /= ss1; next1 /= ss1;
  ft = t * 20.0f; fr = ft - floorf(ft);
  float prev2 = 1.0f - fr, next2 = 1.0f - prev2;
  const float ss2 = prev2 + next2; prev2 /= ss2; next2 /= ss2;

  const float4 xin = reinterpret_cast<const float4*>(xyzs)[n];
  const float px = (xin.x + 1.0f) * 0.5f;
  const float py = (xin.y + 1.0f) * 0.5f;
  const float pz = (xin.z + 1.0f) * 0.5f;

  float h1[64];
  #pragma unroll
  for (int j = 0; j < 64; ++j) h1[j] = 0.0f;

  const size_t f1base = (size_t)4 * NPTS + (size_t)n * 16;
  const size_t f2base = (size_t)20 * NPTS + (size_t)n * 16;

  for (int l = 0; l < LVLS; ++l) {
    const float s = sc.scale[l];
    const int res = sc.res[l];
    const float fx = px * s + 0.5f; const float f0x = floorf(fx); const float wx = fx - f0x;
    const float fy = py * s + 0.5f; const float f0y = floorf(fy); const float wy = fy - f0y;
    const float fz = pz * s + 0.5f; const float f0z = floorf(fz); const float wz = fz - f0z;
    const int ix = (int)f0x, iy = (int)f0y, iz = (int)f0z;

    unsigned idx[8];
    if (sc.dense[l]) {
      const int r2 = res * res;
      const int bx0 = ix,       bx1 = ix + 1;
      const int by0 = iy * res, by1 = by0 + res;
      const int bz0 = iz * r2,  bz1 = bz0 + r2;
      idx[0] = (unsigned)(bx0 + by0 + bz0);
      idx[1] = (unsigned)(bx1 + by0 + bz0);
      idx[2] = (unsigned)(bx0 + by1 + bz0);
      idx[3] = (unsigned)(bx1 + by1 + bz0);
      idx[4] = (unsigned)(bx0 + by0 + bz1);
      idx[5] = (unsigned)(bx1 + by0 + bz1);
      idx[6] = (unsigned)(bx0 + by1 + bz1);
      idx[7] = (unsigned)(bx1 + by1 + bz1);
    } else {
      const unsigned hx0 = (unsigned)ix,      hx1 = hx0 + 1u;
      const unsigned hy0 = (unsigned)iy * P1, hy1 = hy0 + P1;
      const unsigned hz0 = (unsigned)iz * P2, hz1 = hz0 + P2;
      idx[0] = (hx0 ^ hy0 ^ hz0) & TMASK;
      idx[1] = (hx1 ^ hy0 ^ hz0) & TMASK;
      idx[2] = (hx0 ^ hy1 ^ hz0) & TMASK;
      idx[3] = (hx1 ^ hy1 ^ hz0) & TMASK;
      idx[4] = (hx0 ^ hy0 ^ hz1) & TMASK;
      idx[5] = (hx1 ^ hy0 ^ hz1) & TMASK;
      idx[6] = (hx0 ^ hy1 ^ hz1) & TMASK;
      idx[7] = (hx1 ^ hy1 ^ hz1) & TMASK;
    }

    const float wxa = 1.0f - wx, wya = 1.0f - wy, wza = 1.0f - wz;
    float wv[8];
    wv[0] = wxa * wya * wza;
    wv[1] = wx  * wya * wza;
    wv[2] = wxa * wy  * wza;
    wv[3] = wx  * wy  * wza;
    wv[4] = wxa * wya * wz;
    wv[5] = wx  * wya * wz;
    wv[6] = wxa * wy  * wz;
    wv[7] = wx  * wy  * wz;

    float a10 = 0.f, a11 = 0.f, a20 = 0.f, a21 = 0.f;
    float b10 = 0.f, b11 = 0.f, b20 = 0.f, b21 = 0.f;
    float st0 = 0.f, st1 = 0.f;
    const size_t lbase = (size_t)l * TSZ;

    const float2* ba1 = reinterpret_cast<const float2*>(ta1) + lbase;
    const float2* ba2 = reinterpret_cast<const float2*>(ta2) + lbase;
    const float2* bb1 = reinterpret_cast<const float2*>(tb1) + lbase;
    const float2* bb2 = reinterpret_cast<const float2*>(tb2) + lbase;
    const float2* bst = reinterpret_cast<const float2*>(tst) + lbase;
    float2 va1[8], va2[8], vb1[8], vb2[8], vst[8];
    #pragma unroll
    for (int c = 0; c < 8; ++c) {
      const unsigned id = idx[c];
      va1[c] = ba1[id]; va2[c] = ba2[id]; vb1[c] = bb1[id];
      vb2[c] = bb2[id]; vst[c] = bst[id];
    }
    #pragma unroll
    for (int c = 0; c < 8; ++c) {
      const float w = wv[c];
      a10 += va1[c].x * w; a11 += va1[c].y * w;
      a20 += va2[c].x * w; a21 += va2[c].y * w;
      b10 += vb1[c].x * w; b11 += vb1[c].y * w;
      b20 += vb2[c].x * w; b21 += vb2[c].y * w;
      st0 += vst[c].x * w; st1 += vst[c].y * w;
    }

    const float ba0f = a10 * prev1 + a20 * next1;
    const float ba1f = a11 * prev1 + a21 * next1;
    const float bb0f = b10 * prev2 + b20 * next2;
    const float bb1f = b11 * prev2 + b21 * next2;

    const float* wr0 = w1 + (size_t)(2 * l) * 64;
    const float* wr1 = w1 + (size_t)(2 * l + 1) * 64;
    const float* wr2 = w1 + (size_t)(32 + 2 * l) * 64;
    const float* wr3 = w1 + (size_t)(33 + 2 * l) * 64;
    const float* wr4 = w1 + (size_t)(64 + 2 * l) * 64;
    const float* wr5 = w1 + (size_t)(65 + 2 * l) * 64;
    #pragma unroll
    for (int j = 0; j < 64; ++j) {
      float acc = h1[j];
      acc += ba0f * wr0[j];
      acc += ba1f * wr1[j];
      acc += bb0f * wr2[j];
      acc += bb1f * wr3[j];
      acc += st0  * wr4[j];
      acc += st1  * wr5[j];
      h1[j] = acc;
    }

    if (l >= 12) {
      const size_t fo = (size_t)(l - 12) * 2;
      float2* o;
      o = reinterpret_cast<float2*>(out + f1base + fo);     *o = make_float2(a10, a11);
      o = reinterpret_cast<float2*>(out + f1base + 8 + fo); *o = make_float2(b10, b11);
      o = reinterpret_cast<float2*>(out + f2base + fo);     *o = make_float2(a20, a21);
      o = reinterpret_cast<float2*>(out + f2base + 8 + fo); *o = make_float2(b20, b21);
    }
  }

  float h2[16];
  #pragma unroll
  for (int j = 0; j < 16; ++j) h2[j] = 0.0f;
  #pragma unroll
  for (int k = 0; k < 64; ++k) {
    const float a = fmaxf(h1[k], 0.0f);
    #pragma unroll
    for (int j = 0; j < 16; ++j) h2[j] += a * w2[k * 16 + j];
  }
  out[(size_t)3 * NPTS + n] = expf(h2[0]);

  const float dx = dirs[(size_t)n * 3 + 0] * 2.0f - 1.0f;
  const float dy = dirs[(size_t)n * 3 + 1] * 2.0f - 1.0f;
  const float dz = dirs[(size_t)n * 3 + 2] * 2.0f - 1.0f;
  const float xy = dx * dy, xz = dx * dz, yz = dy * dz;
  const float x2 = dx * dx, y2 = dy * dy, z2 = dz * dz;
  float sh[16];
  sh[0]  = 0.28209479177387814f;
  sh[1]  = -0.48860251190291987f * dy;
  sh[2]  = 0.48860251190291987f * dz;
  sh[3]  = -0.48860251190291987f * dx;
  sh[4]  = 1.0925484305920792f * xy;
  sh[5]  = -1.0925484305920792f * yz;
  sh[6]  = 0.94617469575756f * z2 - 0.31539156525252005f;
  sh[7]  = -1.0925484305920792f * xz;
  sh[8]  = 0.5462742152960396f * (x2 - y2);
  sh[9]  = 0.5900435899266435f * dy * (-3.0f * x2 + y2);
  sh[10] = 2.890611442640554f * xy * dz;
  sh[11] = 0.4570457994644657f * dy * (1.0f - 5.0f * z2);
  sh[12] = 0.3731763325901154f * dz * (5.0f * z2 - 3.0f);
  sh[13] = 0.4570457994644657f * dx * (1.0f - 5.0f * z2);
  sh[14] = 1.445305721320277f * dz * (x2 - y2);
  sh[15] = 0.5900435899266435f * dx * (-x2 + 3.0f * y2);

  float r1[64];
  #pragma unroll
  for (int j = 0; j < 64; ++j) r1[j] = 0.0f;
  #pragma unroll
  for (int k = 0; k < 16; ++k) {
    const float a = sh[k];
    #pragma unroll
    for (int j = 0; j < 64; ++j) r1[j] += a * wc1[(size_t)k * 64 + j];
  }
  #pragma unroll
  for (int k = 0; k < 16; ++k) {
    const float a = h2[k];
    #pragma unroll
    for (int j = 0; j < 64; ++j) r1[j] += a * wc1[(size_t)(16 + k) * 64 + j];
  }
  #pragma unroll
  for (int j = 0; j < 64; ++j) r1[j] = fmaxf(r1[j], 0.0f);

  float r2[64];
  #pragma unroll
  for (int j = 0; j < 64; ++j) r2[j] = 0.0f;
  #pragma unroll
  for (int k = 0; k < 64; ++k) {
    const float a = r1[k];
    #pragma unroll
    for (int j = 0; j < 64; ++j) r2[j] += a * wc2[(size_t)k * 64 + j];
  }

  float c0a = 0.f, c1a = 0.f, c2a = 0.f;
  #pragma unroll
  for (int k = 0; k < 64; ++k) {
    const float a = fmaxf(r2[k], 0.0f);
    c0a += a * wc3[k * 3 + 0];
    c1a += a * wc3[k * 3 + 1];
    c2a += a * wc3[k * 3 + 2];
  }
  out[(size_t)n * 3 + 0] = 1.0f / (1.0f + expf(-c0a));
  out[(size_t)n * 3 + 1] = 1.0f / (1.0f + expf(-c1a));
  out[(size_t)n * 3 + 2] = 1.0f / (1.0f + expf(-c2a));
}

extern "C" void kernel_launch(void* const* d_in, const int* in_sizes, int n_in,
                              void* d_out, int out_size, void* d_ws, size_t ws_size,
                              hipStream_t stream) {
  const float* xyzs = (const float*)d_in[0];
  const float* dirs = (const float*)d_in[1];
  const float* ta1  = (const float*)d_in[2];
  const float* ta2  = (const float*)d_in[3];
  const float* tb1  = (const float*)d_in[4];
  const float* tb2  = (const float*)d_in[5];
  const float* tst  = (const float*)d_in[6];
  const float* w1   = (const float*)d_in[7];
  const float* w2   = (const float*)d_in[8];
  const float* wc1  = (const float*)d_in[9];
  const float* wc2  = (const float*)d_in[10];
  const float* wc3  = (const float*)d_in[11];

  Sched sc = {};
  const double B = exp(log(4096.0 / 16.0) / 15.0);
  for (int l = 0; l < LVLS; ++l) {
    const double s = 16.0 * pow(B, (double)l) - 1.0;
    sc.scale[l] = (float)s;
    const int res = (int)ceil(s) + 1;
    sc.res[l] = res;
    sc.dense[l] = ((long long)res * res * res <= (long long)TSZ) ? 1 : 0;
  }

  // unit scheduling: LPT greedy onto 8 XCDs.
  // weights: hashed A/B=3, hashed ST=2, dense=1
  int load[8] = {0}, cnt[8] = {0};
  auto place = [&](int kind, int level, int w) {
    int best = -1;
    for (int k = 0; k < 8; ++k) {
      if (cnt[k] >= MAXU) continue;
      if (best < 0 || load[k] < load[best]) best = k;
    }
    sc.ukind[best][cnt[best]] = (unsigned char)kind;
    sc.ulevel[best][cnt[best]] = (unsigned char)level;
    cnt[best]++; load[best] += w;
  };
  for (int l = 0; l < LVLS; ++l)
    if (!sc.dense[l]) { place(0, l, 3); place(1, l, 3); }
  for (int l = 0; l < LVLS; ++l)
    if (!sc.dense[l]) place(2, l, 2);
  for (int l = 0; l < LVLS; ++l)
    if (sc.dense[l]) { place(0, l, 1); place(1, l, 1); place(2, l, 1); }
  int maxcnt = 0;
  for (int k = 0; k < 8; ++k) {
    sc.nblocks[k] = cnt[k] * 1024;
    if (cnt[k] > maxcnt) maxcnt = cnt[k];
  }

  if (ws_size >= WS_NEED) {
    char* base = (char*)d_ws;
    uint2*    PA   = (uint2*)base;
    uint2*    PB   = (uint2*)(base + PA_BYTES);
    unsigned* PST  = (unsigned*)(base + PA_BYTES + PB_BYTES);
    unsigned* feat = (unsigned*)(base + PA_BYTES + PB_BYTES + PST_BYTES);
    unsigned* wpp  = (unsigned*)(base + PA_BYTES + PB_BYTES + PST_BYTES + FEAT_BYTES);

    repack3<<<(LVLS * TSZ) / 256, 256, 0, stream>>>(
        (const float2*)ta1, (const float2*)ta2, (const float2*)tb1,
        (const float2*)tb2, (const float2*)tst, PA, PB, PST);
    wconv<<<1, 256, 0, stream>>>(w1, w2, wc1, wc2, wpp);
    ngp_gather<<<8 * maxcnt * 1024, 256, 0, stream>>>(
        xyzs, PA, PB, PST, feat, (float*)d_out, sc);
    ngp_mlp<<<NPTS / 256, 256, 0, stream>>>(dirs, feat, wpp, wc3, (float*)d_out);
  } else {
    ngp_fused<<<NPTS / 256, 256, 0, stream>>>(
        xyzs, dirs, ta1, ta2, tb1, tb2, tst,
        w1, w2, wc1, wc2, wc3, (float*)d_out, sc);
  }
}

// Round 6
// 534.818 us; speedup vs baseline: 1.2711x; 1.1003x over previous
//
#include <hip/hip_runtime.h>
#include <cmath>

constexpr int NPTS = 262144;
constexpr int LVLS = 16;
constexpr int TSZ  = 524288;
constexpr unsigned TMASK = TSZ - 1u;
constexpr unsigned P1 = 2654435761u;
constexpr unsigned P2 = 805459861u;

// workspace layout (bytes)
constexpr size_t PAB_BYTES  = (size_t)LVLS * TSZ * 16;  // [a1|a2|b1|b2] fp16x8 = 16B
constexpr size_t PST_BYTES  = (size_t)LVLS * TSZ * 4;   // st fp16x2
constexpr size_t FEAT_BYTES = (size_t)LVLS * 3 * NPTS * 4;
constexpr int    WP_W1 = 0,    WP_W1N = 48 * 64;         // w1 pairs  [48][64]
constexpr int    WP_W2 = 3072, WP_W2N = 32 * 16;         // w2 pairs  [32][16]
constexpr int    WP_C1 = 3584, WP_C1N = 16 * 64;         // wc1 pairs [16][64]
constexpr int    WP_C2 = 4608, WP_C2N = 32 * 64;         // wc2 pairs [32][64]
constexpr size_t WP_BYTES = 6656 * 4;
constexpr size_t WS_NEED = PAB_BYTES + PST_BYTES + FEAT_BYTES + WP_BYTES;

typedef __fp16 half2v __attribute__((ext_vector_type(2)));

__device__ __forceinline__ half2v pkh(float lo, float hi) {
  return __builtin_amdgcn_cvt_pkrtz(lo, hi);
}
__device__ __forceinline__ unsigned pkh2(float lo, float hi) {
  half2v r = __builtin_amdgcn_cvt_pkrtz(lo, hi);
  return *reinterpret_cast<unsigned*>(&r);
}
__device__ __forceinline__ half2v ash2(unsigned w) {
  return *reinterpret_cast<half2v*>(&w);
}
__device__ __forceinline__ float2 uph2(unsigned w) {
  half2v h = ash2(w);
  return make_float2((float)h.x, (float)h.y);
}

#if __has_builtin(__builtin_amdgcn_fdot2)
__device__ __forceinline__ float DOT2(half2v a, half2v b, float c) {
  return __builtin_amdgcn_fdot2(a, b, c, false);
}
#else
__device__ __forceinline__ float DOT2(half2v a, half2v b, float c) {
  return c + (float)a.x * (float)b.x + (float)a.y * (float)b.y;
}
#endif

// scheduling: units = (level, kind) where kind 0=AB(16B merged) 1=ST
constexpr int MAXU = 20;
struct Sched {
  float scale[LVLS];
  int   res[LVLS];
  int   dense[LVLS];
  int   nblocks[8];                 // per-XCD block count (= cnt*1024)
  unsigned char ukind[8][MAXU];
  unsigned char ulevel[8][MAXU];
};

// ---------------- repack: 5 fp32 tables -> merged AB (16B) + ST (4B) ----------------
__global__ __launch_bounds__(256)
void repack2(const float2* __restrict__ ta1, const float2* __restrict__ ta2,
             const float2* __restrict__ tb1, const float2* __restrict__ tb2,
             const float2* __restrict__ tst,
             uint4* __restrict__ PAB, unsigned* __restrict__ PST)
{
  const size_t i = (size_t)blockIdx.x * 256 + threadIdx.x;   // i = l*TSZ + idx
  const float2 a1 = ta1[i], a2 = ta2[i], b1 = tb1[i], b2 = tb2[i], st = tst[i];
  uint4 e;
  e.x = pkh2(a1.x, a1.y);
  e.y = pkh2(a2.x, a2.y);
  e.z = pkh2(b1.x, b1.y);
  e.w = pkh2(b2.x, b2.y);
  PAB[i] = e;
  PST[i] = pkh2(st.x, st.y);
}

// ---------------- weight conversion to fp16 pairs ----------------
__global__ void wconv(const float* __restrict__ w1, const float* __restrict__ w2,
                      const float* __restrict__ wc1, const float* __restrict__ wc2,
                      unsigned* __restrict__ wp)
{
  const int tid = threadIdx.x;
  for (int i = tid; i < WP_W1N; i += 256) {
    const int r = i >> 6, j = i & 63;
    wp[WP_W1 + i] = pkh2(w1[(2 * r) * 64 + j], w1[(2 * r + 1) * 64 + j]);
  }
  for (int i = tid; i < WP_W2N; i += 256) {
    const int r = i >> 4, j = i & 15;
    wp[WP_W2 + i] = pkh2(w2[(2 * r) * 16 + j], w2[(2 * r + 1) * 16 + j]);
  }
  for (int i = tid; i < WP_C1N; i += 256) {
    const int r = i >> 6, j = i & 63;
    wp[WP_C1 + i] = pkh2(wc1[(2 * r) * 64 + j], wc1[(2 * r + 1) * 64 + j]);
  }
  for (int i = tid; i < WP_C2N; i += 256) {
    const int r = i >> 6, j = i & 63;
    wp[WP_C2 + i] = pkh2(wc2[(2 * r) * 64 + j], wc2[(2 * r + 1) * 64 + j]);
  }
}

// ---------------- gather: unit-phased, XCD-affine ----------------
__global__ __launch_bounds__(256)
void ngp_gather(const float* __restrict__ xyzs,
                const uint4* __restrict__ PAB, const unsigned* __restrict__ PST,
                unsigned* __restrict__ feat, float* __restrict__ out, Sched sc)
{
  const int k = blockIdx.x & 7;          // XCD affinity (round-robin heuristic)
  const int j = blockIdx.x >> 3;
  if (j >= sc.nblocks[k]) return;
  const int u = j >> 10;                 // unit slot on this XCD
  const int chunk = j & 1023;
  const int kind = sc.ukind[k][u];
  const int l = sc.ulevel[k][u];
  const int p = (chunk << 8) + threadIdx.x;

  const float4 xin = reinterpret_cast<const float4*>(xyzs)[p];
  const float px = (xin.x + 1.0f) * 0.5f;
  const float py = (xin.y + 1.0f) * 0.5f;
  const float pz = (xin.z + 1.0f) * 0.5f;

  // indices + trilinear weights for level l
  const float s = sc.scale[l];
  const int res = sc.res[l];
  const float fx = px * s + 0.5f; const float f0x = floorf(fx); const float wx = fx - f0x;
  const float fy = py * s + 0.5f; const float f0y = floorf(fy); const float wy = fy - f0y;
  const float fz = pz * s + 0.5f; const float f0z = floorf(fz); const float wz = fz - f0z;
  const int ix = (int)f0x, iy = (int)f0y, iz = (int)f0z;

  unsigned idx[8];
  if (sc.dense[l]) {
    const int r2 = res * res;
    const int bx0 = ix,       bx1 = ix + 1;
    const int by0 = iy * res, by1 = by0 + res;
    const int bz0 = iz * r2,  bz1 = bz0 + r2;
    idx[0] = (unsigned)(bx0 + by0 + bz0);
    idx[1] = (unsigned)(bx1 + by0 + bz0);
    idx[2] = (unsigned)(bx0 + by1 + bz0);
    idx[3] = (unsigned)(bx1 + by1 + bz0);
    idx[4] = (unsigned)(bx0 + by0 + bz1);
    idx[5] = (unsigned)(bx1 + by0 + bz1);
    idx[6] = (unsigned)(bx0 + by1 + bz1);
    idx[7] = (unsigned)(bx1 + by1 + bz1);
  } else {
    const unsigned hx0 = (unsigned)ix,      hx1 = hx0 + 1u;
    const unsigned hy0 = (unsigned)iy * P1, hy1 = hy0 + P1;
    const unsigned hz0 = (unsigned)iz * P2, hz1 = hz0 + P2;
    idx[0] = (hx0 ^ hy0 ^ hz0) & TMASK;
    idx[1] = (hx1 ^ hy0 ^ hz0) & TMASK;
    idx[2] = (hx0 ^ hy1 ^ hz0) & TMASK;
    idx[3] = (hx1 ^ hy1 ^ hz0) & TMASK;
    idx[4] = (hx0 ^ hy0 ^ hz1) & TMASK;
    idx[5] = (hx1 ^ hy0 ^ hz1) & TMASK;
    idx[6] = (hx0 ^ hy1 ^ hz1) & TMASK;
    idx[7] = (hx1 ^ hy1 ^ hz1) & TMASK;
  }

  const float wxa = 1.0f - wx, wya = 1.0f - wy, wza = 1.0f - wz;
  float wv[8];
  wv[0] = wxa * wya * wza;
  wv[1] = wx  * wya * wza;
  wv[2] = wxa * wy  * wza;
  wv[3] = wx  * wy  * wza;
  wv[4] = wxa * wya * wz;
  wv[5] = wx  * wya * wz;
  wv[6] = wxa * wy  * wz;
  wv[7] = wx  * wy  * wz;

  if (kind == 1) {
    // static table: 8 x 4B gathers
    const unsigned* tb = PST + (size_t)l * TSZ;
    unsigned v[8];
    #pragma unroll
    for (int c = 0; c < 8; ++c) v[c] = tb[idx[c]];
    float st0 = 0.f, st1 = 0.f;
    #pragma unroll
    for (int c = 0; c < 8; ++c) {
      const float2 f = uph2(v[c]);
      st0 += f.x * wv[c]; st1 += f.y * wv[c];
    }
    feat[(size_t)(l * 3 + 2) * NPTS + p] = pkh2(st0, st1);
  } else {
    // merged AB: 8 x 16B gathers cover a1,a2,b1,b2
    const float t = xyzs[3];
    float ft = t * 16.0f, fr = ft - floorf(ft);
    float p1w = 1.0f - fr, n1w = 1.0f - p1w;
    const float s1 = p1w + n1w; p1w /= s1; n1w /= s1;
    ft = t * 20.0f; fr = ft - floorf(ft);
    float p2w = 1.0f - fr, n2w = 1.0f - p2w;
    const float s2 = p2w + n2w; p2w /= s2; n2w /= s2;

    const uint4* tb = PAB + (size_t)l * TSZ;
    uint4 m[8];
    #pragma unroll
    for (int c = 0; c < 8; ++c) m[c] = tb[idx[c]];

    float a10 = 0.f, a11 = 0.f, a20 = 0.f, a21 = 0.f;
    float b10 = 0.f, b11 = 0.f, b20 = 0.f, b21 = 0.f;
    #pragma unroll
    for (int c = 0; c < 8; ++c) {
      const float w = wv[c];
      float2 f;
      f = uph2(m[c].x); a10 += f.x * w; a11 += f.y * w;
      f = uph2(m[c].y); a20 += f.x * w; a21 += f.y * w;
      f = uph2(m[c].z); b10 += f.x * w; b11 += f.y * w;
      f = uph2(m[c].w); b20 += f.x * w; b21 += f.y * w;
    }

    const float bla0 = a10 * p1w + a20 * n1w;
    const float bla1 = a11 * p1w + a21 * n1w;
    const float blb0 = b10 * p2w + b20 * n2w;
    const float blb1 = b11 * p2w + b21 * n2w;
    feat[(size_t)(l * 3 + 0) * NPTS + p] = pkh2(bla0, bla1);
    feat[(size_t)(l * 3 + 1) * NPTS + p] = pkh2(blb0, blb1);

    if (l >= 12) {
      const size_t fo = (size_t)(l - 12) * 2;
      const size_t f1base = (size_t)4 * NPTS + (size_t)p * 16;
      const size_t f2base = (size_t)20 * NPTS + (size_t)p * 16;
      *reinterpret_cast<float2*>(out + f1base + fo)     = make_float2(a10, a11);
      *reinterpret_cast<float2*>(out + f1base + 8 + fo) = make_float2(b10, b11);
      *reinterpret_cast<float2*>(out + f2base + fo)     = make_float2(a20, a21);
      *reinterpret_cast<float2*>(out + f2base + 8 + fo) = make_float2(b20, b21);
    }
  }
}

// ---------------- MLP with v_dot2_f32_f16 ----------------
__global__ __launch_bounds__(256)
void ngp_mlp(const float* __restrict__ dirs,
             const unsigned* __restrict__ feat,
             const unsigned* __restrict__ wp,
             const float* __restrict__ wc3,
             float* __restrict__ out)
{
  const int n = blockIdx.x * 256 + threadIdx.x;
  const half2v* w1p = reinterpret_cast<const half2v*>(wp + WP_W1);
  const half2v* w2p = reinterpret_cast<const half2v*>(wp + WP_W2);
  const half2v* c1p = reinterpret_cast<const half2v*>(wp + WP_C1);
  const half2v* c2p = reinterpret_cast<const half2v*>(wp + WP_C2);

  float h1[64];
  #pragma unroll
  for (int j = 0; j < 64; ++j) h1[j] = 0.0f;

  for (int l = 0; l < LVLS; ++l) {
    const half2v A2 = ash2(feat[(size_t)(l * 3 + 0) * NPTS + n]);
    const half2v B2 = ash2(feat[(size_t)(l * 3 + 1) * NPTS + n]);
    const half2v S2 = ash2(feat[(size_t)(l * 3 + 2) * NPTS + n]);
    #pragma unroll
    for (int j = 0; j < 64; ++j) {
      float acc = h1[j];
      acc = DOT2(A2, w1p[l * 64 + j], acc);
      acc = DOT2(B2, w1p[(16 + l) * 64 + j], acc);
      acc = DOT2(S2, w1p[(32 + l) * 64 + j], acc);
      h1[j] = acc;
    }
  }

  // layer 2: h2 = relu(h1) @ w2
  float h2[16];
  #pragma unroll
  for (int j = 0; j < 16; ++j) h2[j] = 0.0f;
  #pragma unroll
  for (int k = 0; k < 32; ++k) {
    const half2v hp = pkh(fmaxf(h1[2 * k], 0.0f), fmaxf(h1[2 * k + 1], 0.0f));
    #pragma unroll
    for (int j = 0; j < 16; ++j) h2[j] = DOT2(hp, w2p[k * 16 + j], h2[j]);
  }

  out[(size_t)3 * NPTS + n] = expf(h2[0]);

  // SH degree 4
  const float dx = dirs[(size_t)n * 3 + 0] * 2.0f - 1.0f;
  const float dy = dirs[(size_t)n * 3 + 1] * 2.0f - 1.0f;
  const float dz = dirs[(size_t)n * 3 + 2] * 2.0f - 1.0f;
  const float xy = dx * dy, xz = dx * dz, yz = dy * dz;
  const float x2 = dx * dx, y2 = dy * dy, z2 = dz * dz;
  float sh[16];
  sh[0]  = 0.28209479177387814f;
  sh[1]  = -0.48860251190291987f * dy;
  sh[2]  = 0.48860251190291987f * dz;
  sh[3]  = -0.48860251190291987f * dx;
  sh[4]  = 1.0925484305920792f * xy;
  sh[5]  = -1.0925484305920792f * yz;
  sh[6]  = 0.94617469575756f * z2 - 0.31539156525252005f;
  sh[7]  = -1.0925484305920792f * xz;
  sh[8]  = 0.5462742152960396f * (x2 - y2);
  sh[9]  = 0.5900435899266435f * dy * (-3.0f * x2 + y2);
  sh[10] = 2.890611442640554f * xy * dz;
  sh[11] = 0.4570457994644657f * dy * (1.0f - 5.0f * z2);
  sh[12] = 0.3731763325901154f * dz * (5.0f * z2 - 3.0f);
  sh[13] = 0.4570457994644657f * dx * (1.0f - 5.0f * z2);
  sh[14] = 1.445305721320277f * dz * (x2 - y2);
  sh[15] = 0.5900435899266435f * dx * (-x2 + 3.0f * y2);

  // c1: r1 = relu(ch @ wc1), ch = [sh | h2] as 16 fp16 pairs
  half2v chp[16];
  #pragma unroll
  for (int r = 0; r < 8; ++r) chp[r] = pkh(sh[2 * r], sh[2 * r + 1]);
  #pragma unroll
  for (int r = 0; r < 8; ++r) chp[8 + r] = pkh(h2[2 * r], h2[2 * r + 1]);
  float r1[64];
  #pragma unroll
  for (int j = 0; j < 64; ++j) r1[j] = 0.0f;
  #pragma unroll
  for (int k = 0; k < 16; ++k) {
    const half2v cp = chp[k];
    #pragma unroll
    for (int j = 0; j < 64; ++j) r1[j] = DOT2(cp, c1p[k * 64 + j], r1[j]);
  }

  // c2: r2 = r1relu @ wc2
  float r2[64];
  #pragma unroll
  for (int j = 0; j < 64; ++j) r2[j] = 0.0f;
  #pragma unroll
  for (int k = 0; k < 32; ++k) {
    const half2v rp = pkh(fmaxf(r1[2 * k], 0.0f), fmaxf(r1[2 * k + 1], 0.0f));
    #pragma unroll
    for (int j = 0; j < 64; ++j) r2[j] = DOT2(rp, c2p[k * 64 + j], r2[j]);
  }

  // c3 + sigmoid (fp32)
  float c0a = 0.f, c1a = 0.f, c2a = 0.f;
  #pragma unroll
  for (int k = 0; k < 64; ++k) {
    const float a = fmaxf(r2[k], 0.0f);
    c0a += a * wc3[k * 3 + 0];
    c1a += a * wc3[k * 3 + 1];
    c2a += a * wc3[k * 3 + 2];
  }
  out[(size_t)n * 3 + 0] = 1.0f / (1.0f + expf(-c0a));
  out[(size_t)n * 3 + 1] = 1.0f / (1.0f + expf(-c1a));
  out[(size_t)n * 3 + 2] = 1.0f / (1.0f + expf(-c2a));
}

// ---------------- fallback: fused fp32 (no workspace) ----------------
__global__ __launch_bounds__(256)
void ngp_fused(const float* __restrict__ xyzs, const float* __restrict__ dirs,
               const float* __restrict__ ta1, const float* __restrict__ ta2,
               const float* __restrict__ tb1, const float* __restrict__ tb2,
               const float* __restrict__ tst,
               const float* __restrict__ w1, const float* __restrict__ w2,
               const float* __restrict__ wc1, const float* __restrict__ wc2,
               const float* __restrict__ wc3, float* __restrict__ out, Sched sc)
{
  const int n = blockIdx.x * 256 + threadIdx.x;
  if (n >= NPTS) return;

  const float t = xyzs[3];
  float ft = t * 16.0f, fr = ft - floorf(ft);
  float prev1 = 1.0f - fr, next1 = 1.0f - prev1;
  const float ss1 = prev1 + next1; prev1 /= ss1; next1 /= ss1;
  ft = t * 20.0f; fr = ft - floorf(ft);
  float prev2 = 1.0f - fr, next2 = 1.0f - prev2;
  const float ss2 = prev2 + next2; prev2 /= ss2; next2 /= ss2;

  const float4 xin = reinterpret_cast<const float4*>(xyzs)[n];
  const float px = (xin.x + 1.0f) * 0.5f;
  const float py = (xin.y + 1.0f) * 0.5f;
  const float pz = (xin.z + 1.0f) * 0.5f;

  float h1[64];
  #pragma unroll
  for (int j = 0; j < 64; ++j) h1[j] = 0.0f;

  const size_t f1base = (size_t)4 * NPTS + (size_t)n * 16;
  const size_t f2base = (size_t)20 * NPTS + (size_t)n * 16;

  for (int l = 0; l < LVLS; ++l) {
    const float s = sc.scale[l];
    const int res = sc.res[l];
    const float fx = px * s + 0.5f; const float f0x = floorf(fx); const float wx = fx - f0x;
    const float fy = py * s + 0.5f; const float f0y = floorf(fy); const float wy = fy - f0y;
    const float fz = pz * s + 0.5f; const float f0z = floorf(fz); const float wz = fz - f0z;
    const int ix = (int)f0x, iy = (int)f0y, iz = (int)f0z;

    unsigned idx[8];
    if (sc.dense[l]) {
      const int r2 = res * res;
      const int bx0 = ix,       bx1 = ix + 1;
      const int by0 = iy * res, by1 = by0 + res;
      const int bz0 = iz * r2,  bz1 = bz0 + r2;
      idx[0] = (unsigned)(bx0 + by0 + bz0);
      idx[1] = (unsigned)(bx1 + by0 + bz0);
      idx[2] = (unsigned)(bx0 + by1 + bz0);
      idx[3] = (unsigned)(bx1 + by1 + bz0);
      idx[4] = (unsigned)(bx0 + by0 + bz1);
      idx[5] = (unsigned)(bx1 + by0 + bz1);
      idx[6] = (unsigned)(bx0 + by1 + bz1);
      idx[7] = (unsigned)(bx1 + by1 + bz1);
    } else {
      const unsigned hx0 = (unsigned)ix,      hx1 = hx0 + 1u;
      const unsigned hy0 = (unsigned)iy * P1, hy1 = hy0 + P1;
      const unsigned hz0 = (unsigned)iz * P2, hz1 = hz0 + P2;
      idx[0] = (hx0 ^ hy0 ^ hz0) & TMASK;
      idx[1] = (hx1 ^ hy0 ^ hz0) & TMASK;
      idx[2] = (hx0 ^ hy1 ^ hz0) & TMASK;
      idx[3] = (hx1 ^ hy1 ^ hz0) & TMASK;
      idx[4] = (hx0 ^ hy0 ^ hz1) & TMASK;
      idx[5] = (hx1 ^ hy0 ^ hz1) & TMASK;
      idx[6] = (hx0 ^ hy1 ^ hz1) & TMASK;
      idx[7] = (hx1 ^ hy1 ^ hz1) & TMASK;
    }

    const float wxa = 1.0f - wx, wya = 1.0f - wy, wza = 1.0f - wz;
    float wv[8];
    wv[0] = wxa * wya * wza;
    wv[1] = wx  * wya * wza;
    wv[2] = wxa * wy  * wza;
    wv[3] = wx  * wy  * wza;
    wv[4] = wxa * wya * wz;
    wv[5] = wx  * wya * wz;
    wv[6] = wxa * wy  * wz;
    wv[7] = wx  * wy  * wz;

    float a10 = 0.f, a11 = 0.f, a20 = 0.f, a21 = 0.f;
    float b10 = 0.f, b11 = 0.f, b20 = 0.f, b21 = 0.f;
    float st0 = 0.f, st1 = 0.f;
    const size_t lbase = (size_t)l * TSZ;

    const float2* ba1 = reinterpret_cast<const float2*>(ta1) + lbase;
    const float2* ba2 = reinterpret_cast<const float2*>(ta2) + lbase;
    const float2* bb1 = reinterpret_cast<const float2*>(tb1) + lbase;
    const float2* bb2 = reinterpret_cast<const float2*>(tb2) + lbase;
    const float2* bst = reinterpret_cast<const float2*>(tst) + lbase;
    float2 va1[8], va2[8], vb1[8], vb2[8], vst[8];
    #pragma unroll
    for (int c = 0; c < 8; ++c) {
      const unsigned id = idx[c];
      va1[c] = ba1[id]; va2[c] = ba2[id]; vb1[c] = bb1[id];
      vb2[c] = bb2[id]; vst[c] = bst[id];
    }
    #pragma unroll
    for (int c = 0; c < 8; ++c) {
      const float w = wv[c];
      a10 += va1[c].x * w; a11 += va1[c].y * w;
      a20 += va2[c].x * w; a21 += va2[c].y * w;
      b10 += vb1[c].x * w; b11 += vb1[c].y * w;
      b20 += vb2[c].x * w; b21 += vb2[c].y * w;
      st0 += vst[c].x * w; st1 += vst[c].y * w;
    }

    const float ba0f = a10 * prev1 + a20 * next1;
    const float ba1f = a11 * prev1 + a21 * next1;
    const float bb0f = b10 * prev2 + b20 * next2;
    const float bb1f = b11 * prev2 + b21 * next2;

    const float* wr0 = w1 + (size_t)(2 * l) * 64;
    const float* wr1 = w1 + (size_t)(2 * l + 1) * 64;
    const float* wr2 = w1 + (size_t)(32 + 2 * l) * 64;
    const float* wr3 = w1 + (size_t)(33 + 2 * l) * 64;
    const float* wr4 = w1 + (size_t)(64 + 2 * l) * 64;
    const float* wr5 = w1 + (size_t)(65 + 2 * l) * 64;
    #pragma unroll
    for (int j = 0; j < 64; ++j) {
      float acc = h1[j];
      acc += ba0f * wr0[j];
      acc += ba1f * wr1[j];
      acc += bb0f * wr2[j];
      acc += bb1f * wr3[j];
      acc += st0  * wr4[j];
      acc += st1  * wr5[j];
      h1[j] = acc;
    }

    if (l >= 12) {
      const size_t fo = (size_t)(l - 12) * 2;
      float2* o;
      o = reinterpret_cast<float2*>(out + f1base + fo);     *o = make_float2(a10, a11);
      o = reinterpret_cast<float2*>(out + f1base + 8 + fo); *o = make_float2(b10, b11);
      o = reinterpret_cast<float2*>(out + f2base + fo);     *o = make_float2(a20, a21);
      o = reinterpret_cast<float2*>(out + f2base + 8 + fo); *o = make_float2(b20, b21);
    }
  }

  float h2[16];
  #pragma unroll
  for (int j = 0; j < 16; ++j) h2[j] = 0.0f;
  #pragma unroll
  for (int k = 0; k < 64; ++k) {
    const float a = fmaxf(h1[k], 0.0f);
    #pragma unroll
    for (int j = 0; j < 16; ++j) h2[j] += a * w2[k * 16 + j];
  }
  out[(size_t)3 * NPTS + n] = expf(h2[0]);

  const float dx = dirs[(size_t)n * 3 + 0] * 2.0f - 1.0f;
  const float dy = dirs[(size_t)n * 3 + 1] * 2.0f - 1.0f;
  const float dz = dirs[(size_t)n * 3 + 2] * 2.0f - 1.0f;
  const float xy = dx * dy, xz = dx * dz, yz = dy * dz;
  const float x2 = dx * dx, y2 = dy * dy, z2 = dz * dz;
  float sh[16];
  sh[0]  = 0.28209479177387814f;
  sh[1]  = -0.48860251190291987f * dy;
  sh[2]  = 0.48860251190291987f * dz;
  sh[3]  = -0.48860251190291987f * dx;
  sh[4]  = 1.0925484305920792f * xy;
  sh[5]  = -1.0925484305920792f * yz;
  sh[6]  = 0.94617469575756f * z2 - 0.31539156525252005f;
  sh[7]  = -1.0925484305920792f * xz;
  sh[8]  = 0.5462742152960396f * (x2 - y2);
  sh[9]  = 0.5900435899266435f * dy * (-3.0f * x2 + y2);
  sh[10] = 2.890611442640554f * xy * dz;
  sh[11] = 0.4570457994644657f * dy * (1.0f - 5.0f * z2);
  sh[12] = 0.3731763325901154f * dz * (5.0f * z2 - 3.0f);
  sh[13] = 0.4570457994644657f * dx * (1.0f - 5.0f * z2);
  sh[14] = 1.445305721320277f * dz * (x2 - y2);
  sh[15] = 0.5900435899266435f * dx * (-x2 + 3.0f * y2);

  float r1[64];
  #pragma unroll
  for (int j = 0; j < 64; ++j) r1[j] = 0.0f;
  #pragma unroll
  for (int k = 0; k < 16; ++k) {
    const float a = sh[k];
    #pragma unroll
    for (int j = 0; j < 64; ++j) r1[j] += a * wc1[(size_t)k * 64 + j];
  }
  #pragma unroll
  for (int k = 0; k < 16; ++k) {
    const float a = h2[k];
    #pragma unroll
    for (int j = 0; j < 64; ++j) r1[j] += a * wc1[(size_t)(16 + k) * 64 + j];
  }
  #pragma unroll
  for (int j = 0; j < 64; ++j) r1[j] = fmaxf(r1[j], 0.0f);

  float r2[64];
  #pragma unroll
  for (int j = 0; j < 64; ++j) r2[j] = 0.0f;
  #pragma unroll
  for (int k = 0; k < 64; ++k) {
    const float a = r1[k];
    #pragma unroll
    for (int j = 0; j < 64; ++j) r2[j] += a * wc2[(size_t)k * 64 + j];
  }

  float c0a = 0.f, c1a = 0.f, c2a = 0.f;
  #pragma unroll
  for (int k = 0; k < 64; ++k) {
    const float a = fmaxf(r2[k], 0.0f);
    c0a += a * wc3[k * 3 + 0];
    c1a += a * wc3[k * 3 + 1];
    c2a += a * wc3[k * 3 + 2];
  }
  out[(size_t)n * 3 + 0] = 1.0f / (1.0f + expf(-c0a));
  out[(size_t)n * 3 + 1] = 1.0f / (1.0f + expf(-c1a));
  out[(size_t)n * 3 + 2] = 1.0f / (1.0f + expf(-c2a));
}

extern "C" void kernel_launch(void* const* d_in, const int* in_sizes, int n_in,
                              void* d_out, int out_size, void* d_ws, size_t ws_size,
                              hipStream_t stream) {
  const float* xyzs = (const float*)d_in[0];
  const float* dirs = (const float*)d_in[1];
  const float* ta1  = (const float*)d_in[2];
  const float* ta2  = (const float*)d_in[3];
  const float* tb1  = (const float*)d_in[4];
  const float* tb2  = (const float*)d_in[5];
  const float* tst  = (const float*)d_in[6];
  const float* w1   = (const float*)d_in[7];
  const float* w2   = (const float*)d_in[8];
  const float* wc1  = (const float*)d_in[9];
  const float* wc2  = (const float*)d_in[10];
  const float* wc3  = (const float*)d_in[11];

  Sched sc = {};
  const double B = exp(log(4096.0 / 16.0) / 15.0);
  for (int l = 0; l < LVLS; ++l) {
    const double s = 16.0 * pow(B, (double)l) - 1.0;
    sc.scale[l] = (float)s;
    const int res = (int)ceil(s) + 1;
    sc.res[l] = res;
    sc.dense[l] = ((long long)res * res * res <= (long long)TSZ) ? 1 : 0;
  }

  // unit scheduling: LPT greedy onto 8 XCDs. AB unit weight 2, ST weight 1.
  int load[8] = {0}, cnt[8] = {0};
  auto place = [&](int kind, int level, int w) {
    int best = -1;
    for (int k = 0; k < 8; ++k) {
      if (cnt[k] >= MAXU) continue;
      if (best < 0 || load[k] < load[best]) best = k;
    }
    sc.ukind[best][cnt[best]] = (unsigned char)kind;
    sc.ulevel[best][cnt[best]] = (unsigned char)level;
    cnt[best]++; load[best] += w;
  };
  for (int l = 0; l < LVLS; ++l) place(0, l, 2);   // merged AB units
  for (int l = 0; l < LVLS; ++l) place(1, l, 1);   // ST units
  int maxcnt = 0;
  for (int k = 0; k < 8; ++k) {
    sc.nblocks[k] = cnt[k] * 1024;
    if (cnt[k] > maxcnt) maxcnt = cnt[k];
  }

  if (ws_size >= WS_NEED) {
    char* base = (char*)d_ws;
    uint4*    PAB  = (uint4*)base;
    unsigned* PST  = (unsigned*)(base + PAB_BYTES);
    unsigned* feat = (unsigned*)(base + PAB_BYTES + PST_BYTES);
    unsigned* wpp  = (unsigned*)(base + PAB_BYTES + PST_BYTES + FEAT_BYTES);

    repack2<<<(LVLS * TSZ) / 256, 256, 0, stream>>>(
        (const float2*)ta1, (const float2*)ta2, (const float2*)tb1,
        (const float2*)tb2, (const float2*)tst, PAB, PST);
    wconv<<<1, 256, 0, stream>>>(w1, w2, wc1, wc2, wpp);
    ngp_gather<<<8 * maxcnt * 1024, 256, 0, stream>>>(
        xyzs, PAB, PST, feat, (float*)d_out, sc);
    ngp_mlp<<<NPTS / 256, 256, 0, stream>>>(dirs, feat, wpp, wc3, (float*)d_out);
  } else {
    ngp_fused<<<NPTS / 256, 256, 0, stream>>>(
        xyzs, dirs, ta1, ta2, tb1, tb2, tst,
        w1, w2, wc1, wc2, wc3, (float*)d_out, sc);
  }
}